// Round 2
// baseline (782.365 us; speedup 1.0000x reference)
//
#include <hip/hip_runtime.h>
#include <hip/hip_bf16.h>
#include <cstdint>

// Problem: B=4, T=2048, D=1024, H=16, HD=64.
// d_out = [ out (4,2048,1024) | k (4,16,2048,64) | v (4,16,2048,64) ] fp32.

typedef short bf16x8 __attribute__((ext_vector_type(8)));
typedef float f32x4 __attribute__((ext_vector_type(4)));

static __device__ __forceinline__ short f2b(float f) {
  union { float f; unsigned u; } x; x.f = f;
  unsigned r = (x.u + 0x7FFFu + ((x.u >> 16) & 1u)) >> 16;   // RNE
  return (short)r;
}

__global__ void cvt_f32_bf16(const float* __restrict__ src, short* __restrict__ dst, int n4) {
  int i = blockIdx.x * blockDim.x + threadIdx.x;
  if (i < n4) {
    float4 v = ((const float4*)src)[i];
    short4 o; o.x = f2b(v.x); o.y = f2b(v.y); o.z = f2b(v.z); o.w = f2b(v.w);
    ((short4*)dst)[i] = o;
  }
}

// C[M=8192][N=1024] = A[8192][1024] @ Bm[1024][1024]^T + bias, bf16 MFMA.
// MODE 0: Q -> bf16 [B,H,T,64]
// MODE 1: K -> fp32 [B,H,T,64] + bf16 [B,H,T,64]
// MODE 2: V -> fp32 [B,H,T,64] + bf16 transposed [B,H,64,T]
// MODE 3: O -> fp32 [M][N]
template <int MODE>
__global__ __launch_bounds__(256) void gemm_bt(
    const short* __restrict__ A, const short* __restrict__ Bm,
    const float* __restrict__ bias,
    float* __restrict__ out_f, short* __restrict__ out_b) {
  __shared__ short As[128 * 32];
  __shared__ short Bs[128 * 32];
  const int t = threadIdx.x;
  const int lane = t & 63;
  const int w = t >> 6;
  const int wm = w >> 1, wn = w & 1;
  const int quad = lane >> 4, l15 = lane & 15;
  const int bm = blockIdx.y, bn = blockIdx.x;

  f32x4 acc[4][4];
  for (int i = 0; i < 4; i++)
    for (int j = 0; j < 4; j++) acc[i][j] = (f32x4){0.f, 0.f, 0.f, 0.f};

  const int c0 = t, c1 = t + 256;
  const int r0 = c0 >> 2, cc0 = c0 & 3;
  const int r1 = c1 >> 2, cc1 = c1 & 3;

  for (int kk = 0; kk < 1024; kk += 32) {
    bf16x8 a0 = *(const bf16x8*)(A + (size_t)(bm * 128 + r0) * 1024 + kk + cc0 * 8);
    bf16x8 a1 = *(const bf16x8*)(A + (size_t)(bm * 128 + r1) * 1024 + kk + cc1 * 8);
    bf16x8 b0 = *(const bf16x8*)(Bm + (size_t)(bn * 128 + r0) * 1024 + kk + cc0 * 8);
    bf16x8 b1 = *(const bf16x8*)(Bm + (size_t)(bn * 128 + r1) * 1024 + kk + cc1 * 8);
    __syncthreads();
    *(bf16x8*)(As + r0 * 32 + cc0 * 8) = a0;
    *(bf16x8*)(As + r1 * 32 + cc1 * 8) = a1;
    *(bf16x8*)(Bs + r0 * 32 + cc0 * 8) = b0;
    *(bf16x8*)(Bs + r1 * 32 + cc1 * 8) = b1;
    __syncthreads();
    bf16x8 af[4], bfr[4];
    for (int mt = 0; mt < 4; mt++)
      af[mt] = *(const bf16x8*)(As + (wm * 64 + mt * 16 + l15) * 32 + quad * 8);
    for (int nt = 0; nt < 4; nt++)
      bfr[nt] = *(const bf16x8*)(Bs + (wn * 64 + nt * 16 + l15) * 32 + quad * 8);
    for (int mt = 0; mt < 4; mt++)
      for (int nt = 0; nt < 4; nt++)
        acc[mt][nt] = __builtin_amdgcn_mfma_f32_16x16x32_bf16(af[mt], bfr[nt], acc[mt][nt], 0, 0, 0);
  }

  for (int mt = 0; mt < 4; mt++) {
    const int row_base = bm * 128 + wm * 64 + mt * 16 + quad * 4;
    for (int nt = 0; nt < 4; nt++) {
      const int col = bn * 128 + wn * 64 + nt * 16 + l15;
      const float bb = bias[col];
      for (int r = 0; r < 4; r++) {
        const int row = row_base + r;
        const float v = acc[mt][nt][r] + bb;
        if (MODE == 3) {
          out_f[(size_t)row * 1024 + col] = v;
        } else {
          const int b = row >> 11, tt = row & 2047;
          const int h = col >> 6, hi = col & 63;
          const size_t idx = (((size_t)(b * 16 + h)) * 2048 + tt) * 64 + hi;
          if (MODE == 0) {
            out_b[idx] = f2b(v);
          } else if (MODE == 1) {
            out_f[idx] = v; out_b[idx] = f2b(v);
          } else {
            out_f[idx] = v;
            out_b[(((size_t)(b * 16 + h)) * 64 + hi) * 2048 + tt] = f2b(v);
          }
        }
      }
    }
  }
}

// Flash attention, S^T form. Grid: (32, B*H), 4 waves/block, wave = 16 queries.
// Per 128-key tile: S^T = K·Q^T (lane l15 owns query q0+l15, regs hold keys),
// per-lane scalar softmax state, P packed to per-wave LDS as [q][key] rows,
// read back as A-fragments for PV.
// Q,K bf16 [B,H,T,64]; V bf16 transposed [B,H,64,T]; out bf16 [B*T][1024].
__global__ __launch_bounds__(256) void attn_fwd(
    const short* __restrict__ Qb, const short* __restrict__ Kb,
    const short* __restrict__ VTb, short* __restrict__ Ob) {
  __shared__ short Plds[4][16 * 144];   // per-wave P: 16 q-rows, stride 144 (pad)
  const int t = threadIdx.x;
  const int w = t >> 6;
  const int lane = t & 63;
  const int quad = lane >> 4, l15 = lane & 15;
  const int bh = blockIdx.y;
  const int b = bh >> 4, h = bh & 15;
  const int qt = gridDim.x - 1 - blockIdx.x;   // heavy blocks dispatch first
  const int q0 = qt * 64 + w * 16;

  const short* Qh = Qb + (size_t)bh * 2048 * 64;
  const short* Kh = Kb + (size_t)bh * 2048 * 64;
  const short* VTh = VTb + (size_t)bh * 64 * 2048;
  short* Pw = &Plds[w][0];

  const bf16x8 qf0 = *(const bf16x8*)(Qh + (q0 + l15) * 64 + quad * 8);
  const bf16x8 qf1 = *(const bf16x8*)(Qh + (q0 + l15) * 64 + quad * 8 + 32);

  float m_q = -1e30f, l_q = 0.f;
  f32x4 o[4];
  for (int nt = 0; nt < 4; nt++) o[nt] = (f32x4){0.f, 0.f, 0.f, 0.f};

  const int ntile = (q0 + 16 + 127) >> 7;
  const float sscale = 0.125f * 1.4426950408889634f;  // hd^-0.5 * log2(e)

  for (int jt = 0; jt < ntile; ++jt) {
    const int j0 = jt << 7;
    float sv[8][4];
    for (int si = 0; si < 8; ++si) {
      const int krow = j0 + si * 16 + l15;
      bf16x8 kf0 = *(const bf16x8*)(Kh + krow * 64 + quad * 8);
      bf16x8 kf1 = *(const bf16x8*)(Kh + krow * 64 + quad * 8 + 32);
      f32x4 z = (f32x4){0.f, 0.f, 0.f, 0.f};
      z = __builtin_amdgcn_mfma_f32_16x16x32_bf16(kf0, qf0, z, 0, 0, 0);
      z = __builtin_amdgcn_mfma_f32_16x16x32_bf16(kf1, qf1, z, 0, 0, 0);
      const int kbase = j0 + si * 16 + quad * 4;
      const int qg = q0 + l15;
      for (int r = 0; r < 4; r++) {
        float x = z[r] * sscale;
        sv[si][r] = (kbase + r > qg) ? -1e30f : x;
      }
    }
    // per-lane softmax over 128 keys for query q0+l15
    float vmax = sv[0][0];
    for (int si = 0; si < 8; si++)
      for (int r = 0; r < 4; r++) vmax = fmaxf(vmax, sv[si][r]);
    vmax = fmaxf(vmax, __shfl_xor(vmax, 16));
    vmax = fmaxf(vmax, __shfl_xor(vmax, 32));
    const float mn = fmaxf(m_q, vmax);
    const float alpha = exp2f(m_q - mn);
    m_q = mn;
    float ssum = 0.f;
    for (int si = 0; si < 8; si++) {
      float p0 = exp2f(sv[si][0] - mn);
      float p1 = exp2f(sv[si][1] - mn);
      float p2 = exp2f(sv[si][2] - mn);
      float p3 = exp2f(sv[si][3] - mn);
      ssum += (p0 + p1) + (p2 + p3);
      short4 pk; pk.x = f2b(p0); pk.y = f2b(p1); pk.z = f2b(p2); pk.w = f2b(p3);
      *(short4*)(Pw + l15 * 144 + si * 16 + quad * 4) = pk;  // key-contiguous b64
    }
    ssum += __shfl_xor(ssum, 16);
    ssum += __shfl_xor(ssum, 32);
    l_q = l_q * alpha + ssum;
    // redistribute alpha to O's C-layout rows (row q = quad*4+r)
    float ar[4];
    for (int r = 0; r < 4; r++) ar[r] = __shfl(alpha, quad * 4 + r);
    for (int nt = 0; nt < 4; nt++)
      for (int r = 0; r < 4; r++) o[nt][r] *= ar[r];
    // PV: A = P[q][k] fragments from LDS, B = V^T rows
    for (int kc = 0; kc < 4; kc++) {
      bf16x8 pf = *(const bf16x8*)(Pw + l15 * 144 + kc * 32 + quad * 8);
      for (int nt = 0; nt < 4; nt++) {
        bf16x8 vf = *(const bf16x8*)(VTh + (nt * 16 + l15) * 2048 + j0 + kc * 32 + quad * 8);
        o[nt] = __builtin_amdgcn_mfma_f32_16x16x32_bf16(pf, vf, o[nt], 0, 0, 0);
      }
    }
  }
  float lr[4];
  for (int r = 0; r < 4; r++) lr[r] = __shfl(l_q, quad * 4 + r);
  for (int nt = 0; nt < 4; nt++) {
    const int col = h * 64 + nt * 16 + l15;
    for (int r = 0; r < 4; r++) {
      const int q = q0 + quad * 4 + r;
      Ob[((size_t)b * 2048 + q) * 1024 + col] = f2b(o[nt][r] / lr[r]);
    }
  }
}

extern "C" void kernel_launch(void* const* d_in, const int* in_sizes, int n_in,
                              void* d_out, int out_size, void* d_ws, size_t ws_size,
                              hipStream_t stream) {
  const float* x  = (const float*)d_in[0];
  const float* Wq = (const float*)d_in[1];
  const float* bq = (const float*)d_in[2];
  const float* Wk = (const float*)d_in[3];
  const float* bk = (const float*)d_in[4];
  const float* Wv = (const float*)d_in[5];
  const float* bv = (const float*)d_in[6];
  const float* Wo = (const float*)d_in[7];
  const float* bo = (const float*)d_in[8];

  float* out   = (float*)d_out;
  float* k_out = out + (size_t)8388608;
  float* v_out = out + (size_t)16777216;

  short* ws  = (short*)d_ws;
  short* xb   = ws;                    // 8388608 elems
  short* wqb  = ws + 8388608;          // 1048576
  short* wkb  = ws + 9437184;
  short* wvb  = ws + 10485760;
  short* wob  = ws + 11534336;
  short* qb   = ws + 12582912;         // 8388608 [B,H,T,64]
  short* kb   = ws + 20971520;         // 8388608 [B,H,T,64]
  short* vtb  = ws + 29360128;         // 8388608 [B,H,64,T]
  short* attb = ws + 37748736;         // 8388608 [B*T,1024]

  cvt_f32_bf16<<<8192, 256, 0, stream>>>(x,  xb,  2097152);
  cvt_f32_bf16<<<1024, 256, 0, stream>>>(Wq, wqb, 262144);
  cvt_f32_bf16<<<1024, 256, 0, stream>>>(Wk, wkb, 262144);
  cvt_f32_bf16<<<1024, 256, 0, stream>>>(Wv, wvb, 262144);
  cvt_f32_bf16<<<1024, 256, 0, stream>>>(Wo, wob, 262144);

  dim3 g(8, 64), blk(256);
  gemm_bt<0><<<g, blk, 0, stream>>>(xb, wqb, bq, nullptr, qb);
  gemm_bt<1><<<g, blk, 0, stream>>>(xb, wkb, bk, k_out, kb);
  gemm_bt<2><<<g, blk, 0, stream>>>(xb, wvb, bv, v_out, vtb);

  attn_fwd<<<dim3(32, 64), 256, 0, stream>>>(qb, kb, vtb, attb);

  gemm_bt<3><<<g, blk, 0, stream>>>(attb, wob, bo, out, nullptr);
}

// Round 3
// 639.314 us; speedup vs baseline: 1.2238x; 1.2238x over previous
//
#include <hip/hip_runtime.h>
#include <hip/hip_bf16.h>
#include <cstdint>

// Problem: B=4, T=2048, D=1024, H=16, HD=64.
// d_out = [ out (4,2048,1024) | k (4,16,2048,64) | v (4,16,2048,64) ] fp32.

typedef short bf16x8 __attribute__((ext_vector_type(8)));
typedef float f32x4 __attribute__((ext_vector_type(4)));

static __device__ __forceinline__ short f2b(float f) {
  union { float f; unsigned u; } x; x.f = f;
  unsigned r = (x.u + 0x7FFFu + ((x.u >> 16) & 1u)) >> 16;   // RNE
  return (short)r;
}

static __device__ __forceinline__ unsigned pack2bf(float a, float b) {
  union { __hip_bfloat162 h; unsigned u; } c;
  c.h = __float22bfloat162_rn(make_float2(a, b));
  return c.u;
}

__global__ void cvt_f32_bf16(const float* __restrict__ src, short* __restrict__ dst, int n4) {
  int i = blockIdx.x * blockDim.x + threadIdx.x;
  if (i < n4) {
    float4 v = ((const float4*)src)[i];
    short4 o; o.x = f2b(v.x); o.y = f2b(v.y); o.z = f2b(v.z); o.w = f2b(v.w);
    ((short4*)dst)[i] = o;
  }
}

// C[M=8192][N=1024] = A[8192][1024] @ Bm[1024][1024]^T + bias, bf16 MFMA.
// MODE 0: Q -> bf16 [B,H,T,64]
// MODE 1: K -> fp32 [B,H,T,64] + bf16 [B,H,T,64]
// MODE 2: V -> fp32 [B,H,T,64] + bf16 transposed [B,H,64,T]
// MODE 3: O -> fp32 [M][N]
template <int MODE>
__global__ __launch_bounds__(256) void gemm_bt(
    const short* __restrict__ A, const short* __restrict__ Bm,
    const float* __restrict__ bias,
    float* __restrict__ out_f, short* __restrict__ out_b) {
  __shared__ short As[128 * 32];
  __shared__ short Bs[128 * 32];
  const int t = threadIdx.x;
  const int lane = t & 63;
  const int w = t >> 6;
  const int wm = w >> 1, wn = w & 1;
  const int quad = lane >> 4, l15 = lane & 15;
  const int bm = blockIdx.y, bn = blockIdx.x;

  f32x4 acc[4][4];
  for (int i = 0; i < 4; i++)
    for (int j = 0; j < 4; j++) acc[i][j] = (f32x4){0.f, 0.f, 0.f, 0.f};

  const int c0 = t, c1 = t + 256;
  const int r0 = c0 >> 2, cc0 = c0 & 3;
  const int r1 = c1 >> 2, cc1 = c1 & 3;

  for (int kk = 0; kk < 1024; kk += 32) {
    bf16x8 a0 = *(const bf16x8*)(A + (size_t)(bm * 128 + r0) * 1024 + kk + cc0 * 8);
    bf16x8 a1 = *(const bf16x8*)(A + (size_t)(bm * 128 + r1) * 1024 + kk + cc1 * 8);
    bf16x8 b0 = *(const bf16x8*)(Bm + (size_t)(bn * 128 + r0) * 1024 + kk + cc0 * 8);
    bf16x8 b1 = *(const bf16x8*)(Bm + (size_t)(bn * 128 + r1) * 1024 + kk + cc1 * 8);
    __syncthreads();
    *(bf16x8*)(As + r0 * 32 + cc0 * 8) = a0;
    *(bf16x8*)(As + r1 * 32 + cc1 * 8) = a1;
    *(bf16x8*)(Bs + r0 * 32 + cc0 * 8) = b0;
    *(bf16x8*)(Bs + r1 * 32 + cc1 * 8) = b1;
    __syncthreads();
    bf16x8 af[4], bfr[4];
    for (int mt = 0; mt < 4; mt++)
      af[mt] = *(const bf16x8*)(As + (wm * 64 + mt * 16 + l15) * 32 + quad * 8);
    for (int nt = 0; nt < 4; nt++)
      bfr[nt] = *(const bf16x8*)(Bs + (wn * 64 + nt * 16 + l15) * 32 + quad * 8);
    for (int mt = 0; mt < 4; mt++)
      for (int nt = 0; nt < 4; nt++)
        acc[mt][nt] = __builtin_amdgcn_mfma_f32_16x16x32_bf16(af[mt], bfr[nt], acc[mt][nt], 0, 0, 0);
  }

  for (int mt = 0; mt < 4; mt++) {
    const int row_base = bm * 128 + wm * 64 + mt * 16 + quad * 4;
    for (int nt = 0; nt < 4; nt++) {
      const int col = bn * 128 + wn * 64 + nt * 16 + l15;
      const float bb = bias[col];
      for (int r = 0; r < 4; r++) {
        const int row = row_base + r;
        const float v = acc[mt][nt][r] + bb;
        if (MODE == 3) {
          out_f[(size_t)row * 1024 + col] = v;
        } else {
          const int b = row >> 11, tt = row & 2047;
          const int h = col >> 6, hi = col & 63;
          const size_t idx = (((size_t)(b * 16 + h)) * 2048 + tt) * 64 + hi;
          if (MODE == 0) {
            out_b[idx] = f2b(v);
          } else if (MODE == 1) {
            out_f[idx] = v; out_b[idx] = f2b(v);
          } else {
            out_f[idx] = v;
            out_b[(((size_t)(b * 16 + h)) * 64 + hi) * 2048 + tt] = f2b(v);
          }
        }
      }
    }
  }
}

// Flash attention, S^T form. Grid: (64=bh, 32), 4 waves/block, wave = 16 queries.
// qt swizzled with blockIdx.x so each CU gets a balanced spread of causal depths
// (with qt tied to a period-32 grid dim, every CU got a FIXED qt -> 16x CU
// imbalance; that was rounds 1-2's real bottleneck).
// P LDS row stride = 136 shorts = 68 dwords == 4 (mod 32): b64 writes land
// exactly 4 dwords/bank (minimum), b128 reads uniform 8/bank -> conflict-free.
__global__ __launch_bounds__(256) void attn_fwd(
    const short* __restrict__ Qb, const short* __restrict__ Kb,
    const short* __restrict__ VTb, short* __restrict__ Ob) {
  __shared__ short Plds[4][16 * 136];   // per-wave P: 16 q-rows, stride 136
  const int t = threadIdx.x;
  const int w = t >> 6;
  const int lane = t & 63;
  const int quad = lane >> 4, l15 = lane & 15;
  const int bh = blockIdx.x;
  const int b = bh >> 4, h = bh & 15;
  const int qt = (blockIdx.y + blockIdx.x) & 31;   // CU load-balance swizzle
  const int q0 = qt * 64 + w * 16;

  const short* Qh = Qb + (size_t)bh * 2048 * 64;
  const short* Kh = Kb + (size_t)bh * 2048 * 64;
  const short* VTh = VTb + (size_t)bh * 64 * 2048;
  short* Pw = &Plds[w][0];

  const bf16x8 qf0 = *(const bf16x8*)(Qh + (q0 + l15) * 64 + quad * 8);
  const bf16x8 qf1 = *(const bf16x8*)(Qh + (q0 + l15) * 64 + quad * 8 + 32);

  float m_q = -1e30f, l_q = 0.f;
  f32x4 o[4];
  for (int nt = 0; nt < 4; nt++) o[nt] = (f32x4){0.f, 0.f, 0.f, 0.f};

  const int ntile = (qt >> 1) + 1;                  // == ceil((q0+16)/128) for all 4 waves
  const float sscale = 0.125f * 1.4426950408889634f;  // hd^-0.5 * log2(e)

  for (int jt = 0; jt < ntile; ++jt) {
    const int j0 = jt << 7;
    float sv[8][4];
    for (int si = 0; si < 8; ++si) {
      const int krow = j0 + si * 16 + l15;
      bf16x8 kf0 = *(const bf16x8*)(Kh + krow * 64 + quad * 8);
      bf16x8 kf1 = *(const bf16x8*)(Kh + krow * 64 + quad * 8 + 32);
      f32x4 z = (f32x4){0.f, 0.f, 0.f, 0.f};
      z = __builtin_amdgcn_mfma_f32_16x16x32_bf16(kf0, qf0, z, 0, 0, 0);
      z = __builtin_amdgcn_mfma_f32_16x16x32_bf16(kf1, qf1, z, 0, 0, 0);
      for (int r = 0; r < 4; r++) sv[si][r] = z[r] * sscale;
    }
    if (jt == ntile - 1) {                          // only the diagonal tile masks
      const int qg = q0 + l15;
      for (int si = 0; si < 8; si++) {
        const int kbase = j0 + si * 16 + quad * 4;
        for (int r = 0; r < 4; r++)
          if (kbase + r > qg) sv[si][r] = -1e30f;
      }
    }
    // per-lane softmax over 128 keys for query q0+l15
    float vmax = sv[0][0];
    for (int si = 0; si < 8; si++)
      for (int r = 0; r < 4; r++) vmax = fmaxf(vmax, sv[si][r]);
    vmax = fmaxf(vmax, __shfl_xor(vmax, 16));
    vmax = fmaxf(vmax, __shfl_xor(vmax, 32));
    const float mn = fmaxf(m_q, vmax);
    const float alpha = exp2f(m_q - mn);
    m_q = mn;
    float ssum = 0.f;
    for (int si = 0; si < 8; si++) {
      float p0 = exp2f(sv[si][0] - mn);
      float p1 = exp2f(sv[si][1] - mn);
      float p2 = exp2f(sv[si][2] - mn);
      float p3 = exp2f(sv[si][3] - mn);
      ssum += (p0 + p1) + (p2 + p3);
      uint2 pk; pk.x = pack2bf(p0, p1); pk.y = pack2bf(p2, p3);
      *(uint2*)(Pw + l15 * 136 + si * 16 + quad * 4) = pk;   // key-contiguous b64
    }
    ssum += __shfl_xor(ssum, 16);
    ssum += __shfl_xor(ssum, 32);
    l_q = l_q * alpha + ssum;
    // redistribute alpha to O's C-layout rows (row q = quad*4+r)
    float ar[4];
    for (int r = 0; r < 4; r++) ar[r] = __shfl(alpha, quad * 4 + r);
    for (int nt = 0; nt < 4; nt++)
      for (int r = 0; r < 4; r++) o[nt][r] *= ar[r];
    // PV: A = P[q][k] fragments from LDS, B = V^T rows
    for (int kc = 0; kc < 4; kc++) {
      bf16x8 pf = *(const bf16x8*)(Pw + l15 * 136 + kc * 32 + quad * 8);
      for (int nt = 0; nt < 4; nt++) {
        bf16x8 vf = *(const bf16x8*)(VTh + (nt * 16 + l15) * 2048 + j0 + kc * 32 + quad * 8);
        o[nt] = __builtin_amdgcn_mfma_f32_16x16x32_bf16(pf, vf, o[nt], 0, 0, 0);
      }
    }
  }
  float lr[4];
  for (int r = 0; r < 4; r++) lr[r] = __shfl(l_q, quad * 4 + r);
  for (int nt = 0; nt < 4; nt++) {
    const int col = h * 64 + nt * 16 + l15;
    for (int r = 0; r < 4; r++) {
      const int q = q0 + quad * 4 + r;
      Ob[((size_t)b * 2048 + q) * 1024 + col] = f2b(o[nt][r] / lr[r]);
    }
  }
}

extern "C" void kernel_launch(void* const* d_in, const int* in_sizes, int n_in,
                              void* d_out, int out_size, void* d_ws, size_t ws_size,
                              hipStream_t stream) {
  const float* x  = (const float*)d_in[0];
  const float* Wq = (const float*)d_in[1];
  const float* bq = (const float*)d_in[2];
  const float* Wk = (const float*)d_in[3];
  const float* bk = (const float*)d_in[4];
  const float* Wv = (const float*)d_in[5];
  const float* bv = (const float*)d_in[6];
  const float* Wo = (const float*)d_in[7];
  const float* bo = (const float*)d_in[8];

  float* out   = (float*)d_out;
  float* k_out = out + (size_t)8388608;
  float* v_out = out + (size_t)16777216;

  short* ws  = (short*)d_ws;
  short* xb   = ws;                    // 8388608 elems
  short* wqb  = ws + 8388608;          // 1048576
  short* wkb  = ws + 9437184;
  short* wvb  = ws + 10485760;
  short* wob  = ws + 11534336;
  short* qb   = ws + 12582912;         // 8388608 [B,H,T,64]
  short* kb   = ws + 20971520;         // 8388608 [B,H,T,64]
  short* vtb  = ws + 29360128;         // 8388608 [B,H,64,T]
  short* attb = ws + 37748736;         // 8388608 [B*T,1024]

  cvt_f32_bf16<<<8192, 256, 0, stream>>>(x,  xb,  2097152);
  cvt_f32_bf16<<<1024, 256, 0, stream>>>(Wq, wqb, 262144);
  cvt_f32_bf16<<<1024, 256, 0, stream>>>(Wk, wkb, 262144);
  cvt_f32_bf16<<<1024, 256, 0, stream>>>(Wv, wvb, 262144);
  cvt_f32_bf16<<<1024, 256, 0, stream>>>(Wo, wob, 262144);

  dim3 g(8, 64), blk(256);
  gemm_bt<0><<<g, blk, 0, stream>>>(xb, wqb, bq, nullptr, qb);
  gemm_bt<1><<<g, blk, 0, stream>>>(xb, wkb, bk, k_out, kb);
  gemm_bt<2><<<g, blk, 0, stream>>>(xb, wvb, bv, v_out, vtb);

  attn_fwd<<<dim3(64, 32), 256, 0, stream>>>(qb, kb, vtb, attb);

  gemm_bt<3><<<g, blk, 0, stream>>>(attb, wob, bo, out, nullptr);
}

// Round 4
// 401.444 us; speedup vs baseline: 1.9489x; 1.5925x over previous
//
#include <hip/hip_runtime.h>
#include <hip/hip_bf16.h>
#include <cstdint>

// Problem: B=4, T=2048, D=1024, H=16, HD=64.
// d_out = [ out (4,2048,1024) | k (4,16,2048,64) | v (4,16,2048,64) ] fp32.

typedef short bf16x8 __attribute__((ext_vector_type(8)));
typedef float f32x4 __attribute__((ext_vector_type(4)));

#define GLDS16(g, l)                                                          \
  __builtin_amdgcn_global_load_lds(                                           \
      (const __attribute__((address_space(1))) void*)(g),                     \
      (__attribute__((address_space(3))) void*)(l), 16, 0, 0)

static __device__ __forceinline__ short f2b(float f) {
  union { float f; unsigned u; } x; x.f = f;
  unsigned r = (x.u + 0x7FFFu + ((x.u >> 16) & 1u)) >> 16;   // RNE
  return (short)r;
}

static __device__ __forceinline__ unsigned pack2bf(float a, float b) {
  union { __hip_bfloat162 h; unsigned u; } c;
  c.h = __float22bfloat162_rn(make_float2(a, b));
  return c.u;
}

__global__ void cvt_f32_bf16(const float* __restrict__ src, short* __restrict__ dst, int n4) {
  int i = blockIdx.x * blockDim.x + threadIdx.x;
  if (i < n4) {
    float4 v = ((const float4*)src)[i];
    short4 o; o.x = f2b(v.x); o.y = f2b(v.y); o.z = f2b(v.z); o.w = f2b(v.w);
    ((short4*)dst)[i] = o;
  }
}

// C[M=8192][N=1024] = A[8192][1024] @ Bm[1024][1024]^T + bias, bf16 MFMA.
// Staging via global_load_lds width=16 (m97 pattern; [128][32] unpadded tile,
// row stride 16 dwords == 16 mod 32 -> minimum 8 dwords/bank on b128 reads).
template <int MODE>
__global__ __launch_bounds__(256) void gemm_bt(
    const short* __restrict__ A, const short* __restrict__ Bm,
    const float* __restrict__ bias,
    float* __restrict__ out_f, short* __restrict__ out_b) {
  __shared__ short As[128 * 32];
  __shared__ short Bs[128 * 32];
  const int t = threadIdx.x;
  const int lane = t & 63;
  const int w = t >> 6;
  const int wm = w >> 1, wn = w & 1;
  const int quad = lane >> 4, l15 = lane & 15;
  const int bm = blockIdx.y, bn = blockIdx.x;

  f32x4 acc[4][4];
  for (int i = 0; i < 4; i++)
    for (int j = 0; j < 4; j++) acc[i][j] = (f32x4){0.f, 0.f, 0.f, 0.f};

  const int c0 = t, c1 = t + 256;
  const int r0 = c0 >> 2, cc0 = c0 & 3;
  const int r1 = c1 >> 2, cc1 = c1 & 3;
  const short* Abase = A + (size_t)bm * 128 * 1024;
  const short* Bbase = Bm + (size_t)bn * 128 * 1024;

  for (int kk = 0; kk < 1024; kk += 32) {
    __syncthreads();   // readers of previous tile done
    GLDS16(Abase + (size_t)r0 * 1024 + kk + cc0 * 8, &As[c0 * 8]);
    GLDS16(Abase + (size_t)r1 * 1024 + kk + cc1 * 8, &As[c1 * 8]);
    GLDS16(Bbase + (size_t)r0 * 1024 + kk + cc0 * 8, &Bs[c0 * 8]);
    GLDS16(Bbase + (size_t)r1 * 1024 + kk + cc1 * 8, &Bs[c1 * 8]);
    __syncthreads();   // staging complete (vmcnt drained)
    bf16x8 af[4], bfr[4];
    for (int mt = 0; mt < 4; mt++)
      af[mt] = *(const bf16x8*)(As + (wm * 64 + mt * 16 + l15) * 32 + quad * 8);
    for (int nt = 0; nt < 4; nt++)
      bfr[nt] = *(const bf16x8*)(Bs + (wn * 64 + nt * 16 + l15) * 32 + quad * 8);
    for (int mt = 0; mt < 4; mt++)
      for (int nt = 0; nt < 4; nt++)
        acc[mt][nt] = __builtin_amdgcn_mfma_f32_16x16x32_bf16(af[mt], bfr[nt], acc[mt][nt], 0, 0, 0);
  }

  for (int mt = 0; mt < 4; mt++) {
    const int row_base = bm * 128 + wm * 64 + mt * 16 + quad * 4;
    for (int nt = 0; nt < 4; nt++) {
      const int col = bn * 128 + wn * 64 + nt * 16 + l15;
      const float bb = bias[col];
      for (int r = 0; r < 4; r++) {
        const int row = row_base + r;
        const float v = acc[mt][nt][r] + bb;
        if (MODE == 3) {
          out_f[(size_t)row * 1024 + col] = v;
        } else {
          const int b = row >> 11, tt = row & 2047;
          const int h = col >> 6, hi = col & 63;
          const size_t idx = (((size_t)(b * 16 + h)) * 2048 + tt) * 64 + hi;
          if (MODE == 0) {
            out_b[idx] = f2b(v);
          } else if (MODE == 1) {
            out_f[idx] = v; out_b[idx] = f2b(v);
          } else {
            out_f[idx] = v;
            out_b[(((size_t)(b * 16 + h)) * 64 + hi) * 2048 + tt] = f2b(v);
          }
        }
      }
    }
  }
}

// Flash attention, S^T form + cooperative LDS staging of K/V tiles.
// Grid (32 qt-slot, 64 bh), 4 waves/block, wave = 16 queries, Bc = 128 keys.
// K tile [128 rows][8 chunks], VT tile [64 rows][16 chunks]; chunk column is
// XOR-swizzled with (row&7) AT THE GLOBAL SOURCE so the LDS tile stays
// contiguous (global_load_lds requirement) yet b128 reads land at the
// 8-dwords/bank minimum.
__global__ __launch_bounds__(256) void attn_fwd(
    const short* __restrict__ Qb, const short* __restrict__ Kb,
    const short* __restrict__ VTb, short* __restrict__ Ob) {
  __shared__ short Ks[128 * 64];        // 16 KB
  __shared__ short VTs[64 * 128];       // 16 KB
  __shared__ short Plds[4][16 * 136];   // per-wave P, stride 136
  const int t = threadIdx.x;
  const int w = t >> 6;
  const int lane = t & 63;
  const int quad = lane >> 4, l15 = lane & 15;
  const int bh = blockIdx.y;
  const int b = bh >> 4, h = bh & 15;
  const int qt = (blockIdx.x + blockIdx.y) & 31;   // CU load-balance swizzle
  const int q0 = qt * 64 + w * 16;

  const short* Qh = Qb + (size_t)bh * 2048 * 64;
  const short* Kh = Kb + (size_t)bh * 2048 * 64;
  const short* VTh = VTb + (size_t)bh * 64 * 2048;
  short* Pw = &Plds[w][0];

  const bf16x8 qf0 = *(const bf16x8*)(Qh + (q0 + l15) * 64 + quad * 8);
  const bf16x8 qf1 = *(const bf16x8*)(Qh + (q0 + l15) * 64 + quad * 8 + 32);

  float m_q = -1e30f, l_q = 0.f;
  f32x4 o[4];
  for (int nt = 0; nt < 4; nt++) o[nt] = (f32x4){0.f, 0.f, 0.f, 0.f};

  const int ntile = (qt >> 1) + 1;
  const float sscale = 0.125f * 1.4426950408889634f;  // hd^-0.5 * log2(e)

  // per-thread staging descriptors (4 rounds each for K and VT)
  for (int jt = 0; jt < ntile; ++jt) {
    const int j0 = jt << 7;
    __syncthreads();   // previous tile's readers done
    for (int rr = 0; rr < 4; rr++) {
      const int c = rr * 256 + t;
      const int row = c >> 3, colL = c & 7;
      const int colg = colL ^ (row & 7);
      GLDS16(Kh + (size_t)(j0 + row) * 64 + colg * 8, &Ks[c * 8]);
    }
    for (int rr = 0; rr < 4; rr++) {
      const int c = rr * 256 + t;
      const int row = c >> 4, colL = c & 15;
      const int colg = colL ^ (row & 7);
      GLDS16(VTh + (size_t)row * 2048 + j0 + colg * 8, &VTs[c * 8]);
    }
    __syncthreads();   // staging complete

    float sv[8][4];
    for (int si = 0; si < 8; ++si) {
      const int r = si * 16 + l15;
      bf16x8 kf0 = *(const bf16x8*)&Ks[(r * 8 + (quad ^ (r & 7))) * 8];
      bf16x8 kf1 = *(const bf16x8*)&Ks[(r * 8 + ((quad ^ 4) ^ (r & 7))) * 8];
      f32x4 z = (f32x4){0.f, 0.f, 0.f, 0.f};
      z = __builtin_amdgcn_mfma_f32_16x16x32_bf16(kf0, qf0, z, 0, 0, 0);
      z = __builtin_amdgcn_mfma_f32_16x16x32_bf16(kf1, qf1, z, 0, 0, 0);
      for (int r4 = 0; r4 < 4; r4++) sv[si][r4] = z[r4] * sscale;
    }
    if (jt == ntile - 1) {                          // only the diagonal tile masks
      const int qg = q0 + l15;
      for (int si = 0; si < 8; si++) {
        const int kbase = j0 + si * 16 + quad * 4;
        for (int r4 = 0; r4 < 4; r4++)
          if (kbase + r4 > qg) sv[si][r4] = -1e30f;
      }
    }
    // per-lane softmax over 128 keys for query q0+l15
    float vmax = sv[0][0];
    for (int si = 0; si < 8; si++)
      for (int r4 = 0; r4 < 4; r4++) vmax = fmaxf(vmax, sv[si][r4]);
    vmax = fmaxf(vmax, __shfl_xor(vmax, 16));
    vmax = fmaxf(vmax, __shfl_xor(vmax, 32));
    const float mn = fmaxf(m_q, vmax);
    const float alpha = exp2f(m_q - mn);
    m_q = mn;
    float ssum = 0.f;
    for (int si = 0; si < 8; si++) {
      float p0 = exp2f(sv[si][0] - mn);
      float p1 = exp2f(sv[si][1] - mn);
      float p2 = exp2f(sv[si][2] - mn);
      float p3 = exp2f(sv[si][3] - mn);
      ssum += (p0 + p1) + (p2 + p3);
      uint2 pk; pk.x = pack2bf(p0, p1); pk.y = pack2bf(p2, p3);
      *(uint2*)(Pw + l15 * 136 + si * 16 + quad * 4) = pk;   // key-contiguous b64
    }
    ssum += __shfl_xor(ssum, 16);
    ssum += __shfl_xor(ssum, 32);
    l_q = l_q * alpha + ssum;
    // redistribute alpha to O's C-layout rows (row q = quad*4+r)
    float ar[4];
    for (int r4 = 0; r4 < 4; r4++) ar[r4] = __shfl(alpha, quad * 4 + r4);
    for (int nt = 0; nt < 4; nt++)
      for (int r4 = 0; r4 < 4; r4++) o[nt][r4] *= ar[r4];
    // PV: A = P[q][k] from per-wave LDS, B = V^T rows from staged tile
    for (int kc = 0; kc < 4; kc++) {
      bf16x8 pf = *(const bf16x8*)(Pw + l15 * 136 + kc * 32 + quad * 8);
      for (int nt = 0; nt < 4; nt++) {
        const int rv = nt * 16 + l15;
        bf16x8 vf = *(const bf16x8*)&VTs[(rv * 16 + ((kc * 4 + quad) ^ (rv & 7))) * 8];
        o[nt] = __builtin_amdgcn_mfma_f32_16x16x32_bf16(pf, vf, o[nt], 0, 0, 0);
      }
    }
  }
  float lr[4];
  for (int r4 = 0; r4 < 4; r4++) lr[r4] = __shfl(l_q, quad * 4 + r4);
  for (int nt = 0; nt < 4; nt++) {
    const int col = h * 64 + nt * 16 + l15;
    for (int r4 = 0; r4 < 4; r4++) {
      const int q = q0 + quad * 4 + r4;
      Ob[((size_t)b * 2048 + q) * 1024 + col] = f2b(o[nt][r4] / lr[r4]);
    }
  }
}

extern "C" void kernel_launch(void* const* d_in, const int* in_sizes, int n_in,
                              void* d_out, int out_size, void* d_ws, size_t ws_size,
                              hipStream_t stream) {
  const float* x  = (const float*)d_in[0];
  const float* Wq = (const float*)d_in[1];
  const float* bq = (const float*)d_in[2];
  const float* Wk = (const float*)d_in[3];
  const float* bk = (const float*)d_in[4];
  const float* Wv = (const float*)d_in[5];
  const float* bv = (const float*)d_in[6];
  const float* Wo = (const float*)d_in[7];
  const float* bo = (const float*)d_in[8];

  float* out   = (float*)d_out;
  float* k_out = out + (size_t)8388608;
  float* v_out = out + (size_t)16777216;

  short* ws  = (short*)d_ws;
  short* xb   = ws;                    // 8388608 elems
  short* wqb  = ws + 8388608;          // 1048576
  short* wkb  = ws + 9437184;
  short* wvb  = ws + 10485760;
  short* wob  = ws + 11534336;
  short* qb   = ws + 12582912;         // 8388608 [B,H,T,64]
  short* kb   = ws + 20971520;         // 8388608 [B,H,T,64]
  short* vtb  = ws + 29360128;         // 8388608 [B,H,64,T]
  short* attb = ws + 37748736;         // 8388608 [B*T,1024]

  cvt_f32_bf16<<<8192, 256, 0, stream>>>(x,  xb,  2097152);
  cvt_f32_bf16<<<1024, 256, 0, stream>>>(Wq, wqb, 262144);
  cvt_f32_bf16<<<1024, 256, 0, stream>>>(Wk, wkb, 262144);
  cvt_f32_bf16<<<1024, 256, 0, stream>>>(Wv, wvb, 262144);
  cvt_f32_bf16<<<1024, 256, 0, stream>>>(Wo, wob, 262144);

  dim3 g(8, 64), blk(256);
  gemm_bt<0><<<g, blk, 0, stream>>>(xb, wqb, bq, nullptr, qb);
  gemm_bt<1><<<g, blk, 0, stream>>>(xb, wkb, bk, k_out, kb);
  gemm_bt<2><<<g, blk, 0, stream>>>(xb, wvb, bv, v_out, vtb);

  attn_fwd<<<dim3(32, 64), 256, 0, stream>>>(qb, kb, vtb, attb);

  gemm_bt<3><<<g, blk, 0, stream>>>(attb, wob, bo, out, nullptr);
}